// Round 1
// baseline (74.570 us; speedup 1.0000x reference)
//
#include <hip/hip_runtime.h>

// UltralyticsDetect head, fused: per-level 1x1-conv GEMM (M=144, K=C, N=B*HW)
// in bf16 MFMA + in-register DFL softmax decode + output assembly.
// Output: (16, 8400, 84) f32.

typedef __bf16 bf16x8 __attribute__((ext_vector_type(8)));
typedef float  f32x4  __attribute__((ext_vector_type(4)));

#define NTHREADS 256

// round-half-up f32 -> bf16, pack two into one u32 (a -> low16, b -> high16)
__device__ __forceinline__ unsigned int pack_bf16(float a, float b) {
    unsigned int ua = __builtin_bit_cast(unsigned int, a);
    unsigned int ub = __builtin_bit_cast(unsigned int, b);
    return ((ua + 0x8000u) >> 16) | ((ub + 0x8000u) & 0xffff0000u);
}

// LDS tile: row-major [row][64 bf16] = 128B rows, XOR-swizzled to kill the
// 32-way ds_read_b128 bank conflict (G4: byte ^= (row&7)<<4).
__device__ __forceinline__ int swz(int row, int kbyte) {
    return row * 128 + (kbyte ^ ((row & 7) << 4));
}

template <int LVL>
__device__ __forceinline__ void run_level(
        int rb,
        const float* __restrict__ x,
        const float* __restrict__ wbox, const float* __restrict__ bbox,
        const float* __restrict__ wcls, const float* __restrict__ bcls,
        float* __restrict__ out,
        unsigned char* s_w, unsigned char* s_x) {

    constexpr int   C      = (LVL == 0) ? 256 : 512;
    constexpr int   GW     = (LVL == 0) ? 80 : (LVL == 1 ? 40 : 20);
    constexpr int   HW     = GW * GW;
    constexpr int   AOFF   = (LVL == 0) ? 0 : (LVL == 1 ? 6400 : 8000);
    constexpr float STRIDE = (LVL == 0) ? 8.0f : (LVL == 1 ? 16.0f : 32.0f);
    constexpr int   TPB    = (HW + 127) / 128;   // tiles per batch image

    const int b    = rb / TPB;
    const int tile = rb % TPB;
    const int hw0  = tile * 128;
    const int nv   = (HW - hw0 < 128) ? (HW - hw0) : 128;  // valid anchors

    const int tid  = threadIdx.x;
    const int wv   = tid >> 6;        // wave 0..3
    const int lane = tid & 63;
    const int col  = lane & 15;       // MFMA n/col lane
    const int q4   = lane >> 4;       // MFMA row-quarter

    const float* xb = x + (size_t)b * C * HW;

    // X staging assignment: thread -> (anchor, even/odd k-groups)
    const int anc = tid & 127;
    const int kgb = tid >> 7;                       // 0 or 1
    const int ancc = (anc < nv) ? anc : (nv - 1);   // clamp OOB anchors
    const float* xcol = xb + hw0 + ancc;

    f32x4 acc[9][2];
#pragma unroll
    for (int m = 0; m < 9; ++m)
#pragma unroll
        for (int n = 0; n < 2; ++n)
            acc[m][n] = (f32x4){0.f, 0.f, 0.f, 0.f};

    const int nkc = C / 64;
    for (int kc = 0; kc < nkc; ++kc) {
        const int k0 = kc * 64;
        __syncthreads();   // previous iteration's reads complete

        // ---- stage W chunk: 144 rows x 64 k, f32 -> bf16, swizzled ----
        // 1152 units of 8 k-elems
#pragma unroll
        for (int i = 0; i < 5; ++i) {
            int u = tid + i * 256;
            if (u < 1152) {
                int row = u >> 3, kg = u & 7;
                const float* src = (row < 64) ? (wbox + row * C)
                                              : (wcls + (row - 64) * C);
                src += k0 + kg * 8;
                const float4 f0 = *(const float4*)(src);
                const float4 f1 = *(const float4*)(src + 4);
                uint4 p;
                p.x = pack_bf16(f0.x, f0.y);
                p.y = pack_bf16(f0.z, f0.w);
                p.z = pack_bf16(f1.x, f1.y);
                p.w = pack_bf16(f1.z, f1.w);
                *(uint4*)(s_w + swz(row, kg * 16)) = p;
            }
        }

        // ---- stage X chunk: transpose [c][hw] -> [anchor][k], bf16 ----
#pragma unroll
        for (int i = 0; i < 4; ++i) {
            const int kg = kgb + 2 * i;
            const float* p = xcol + (size_t)(k0 + kg * 8) * HW;
            float v[8];
#pragma unroll
            for (int j = 0; j < 8; ++j) v[j] = p[(size_t)j * HW];
            uint4 q;
            q.x = pack_bf16(v[0], v[1]);
            q.y = pack_bf16(v[2], v[3]);
            q.z = pack_bf16(v[4], v[5]);
            q.w = pack_bf16(v[6], v[7]);
            *(uint4*)(s_x + swz(anc, kg * 16)) = q;
        }

        __syncthreads();

        // ---- MFMA: 2 k-steps of 32, 9 M-tiles x 2 N-tiles per wave ----
#pragma unroll
        for (int ks = 0; ks < 2; ++ks) {
            const int kbyte = ks * 64 + q4 * 16;
            const bf16x8 bf0 = *(const bf16x8*)(s_x + swz(wv * 32 + col, kbyte));
            const bf16x8 bf1 = *(const bf16x8*)(s_x + swz(wv * 32 + 16 + col, kbyte));
#pragma unroll
            for (int m = 0; m < 9; ++m) {
                const bf16x8 af = *(const bf16x8*)(s_w + swz(m * 16 + col, kbyte));
                acc[m][0] = __builtin_amdgcn_mfma_f32_16x16x32_bf16(af, bf0, acc[m][0], 0, 0, 0);
                acc[m][1] = __builtin_amdgcn_mfma_f32_16x16x32_bf16(af, bf1, acc[m][1], 0, 0, 0);
            }
        }
    }

    // ---- epilogue: in-register DFL decode + store ----
    // D layout (m89): value[r] = D[mtile*16 + q4*4 + r][col]
    float4 bcv[5];
#pragma unroll
    for (int m = 0; m < 5; ++m)
        bcv[m] = *(const float4*)(bcls + m * 16 + q4 * 4);

    const float LOG2E = 1.44269504088896f;

#pragma unroll
    for (int nt = 0; nt < 2; ++nt) {
        const int alocal = wv * 32 + nt * 16 + col;
        const bool valid = alocal < nv;
        const int hw = hw0 + alocal;

        float dist[4];
#pragma unroll
        for (int g = 0; g < 4; ++g) {
            const float4 bbv = *(const float4*)(bbox + g * 16 + q4 * 4);
            const float v0 = acc[g][nt][0] + bbv.x;
            const float v1 = acc[g][nt][1] + bbv.y;
            const float v2 = acc[g][nt][2] + bbv.z;
            const float v3 = acc[g][nt][3] + bbv.w;
            // softmax over 16 bins: 4 regs x 4 lanes (col, col+16, col+32, col+48)
            float mx = fmaxf(fmaxf(v0, v1), fmaxf(v2, v3));
            mx = fmaxf(mx, __shfl_xor(mx, 16));
            mx = fmaxf(mx, __shfl_xor(mx, 32));
            const float e0 = __builtin_amdgcn_exp2f((v0 - mx) * LOG2E);
            const float e1 = __builtin_amdgcn_exp2f((v1 - mx) * LOG2E);
            const float e2 = __builtin_amdgcn_exp2f((v2 - mx) * LOG2E);
            const float e3 = __builtin_amdgcn_exp2f((v3 - mx) * LOG2E);
            float s  = e0 + e1 + e2 + e3;
            float ws = e1 + 2.f * e2 + 3.f * e3 + (float)(q4 * 4) * s;
            s  += __shfl_xor(s, 16);
            s  += __shfl_xor(s, 32);
            ws += __shfl_xor(ws, 16);
            ws += __shfl_xor(ws, 32);
            dist[g] = ws / s;
        }

        if (valid) {
            const size_t obase = ((size_t)b * 8400 + AOFF + hw) * 84;
            if (q4 == 0) {
                const float ax = (float)(hw % GW) + 0.5f;
                const float ay = (float)(hw / GW) + 0.5f;
                float4 bx;
                bx.x = (ax + 0.5f * (dist[2] - dist[0])) * STRIDE;
                bx.y = (ay + 0.5f * (dist[3] - dist[1])) * STRIDE;
                bx.z = (dist[0] + dist[2]) * STRIDE;
                bx.w = (dist[1] + dist[3]) * STRIDE;
                *(float4*)(out + obase) = bx;
            }
#pragma unroll
            for (int m = 0; m < 5; ++m) {
                float4 v;
                v.x = acc[m + 4][nt][0] + bcv[m].x;
                v.y = acc[m + 4][nt][1] + bcv[m].y;
                v.z = acc[m + 4][nt][2] + bcv[m].z;
                v.w = acc[m + 4][nt][3] + bcv[m].w;
                *(float4*)(out + obase + 4 + m * 16 + q4 * 4) = v;
            }
        }
    }
}

__global__ __launch_bounds__(NTHREADS, 2)
void UltralyticsDetect_kernel(
        const float* __restrict__ x0, const float* __restrict__ x1, const float* __restrict__ x2,
        const float* __restrict__ wb0, const float* __restrict__ bb0,
        const float* __restrict__ wc0, const float* __restrict__ bc0,
        const float* __restrict__ wb1, const float* __restrict__ bb1,
        const float* __restrict__ wc1, const float* __restrict__ bc1,
        const float* __restrict__ wb2, const float* __restrict__ bb2,
        const float* __restrict__ wc2, const float* __restrict__ bc2,
        float* __restrict__ out) {

    __shared__ __align__(16) unsigned char s_w[144 * 64 * 2];  // 18 KiB
    __shared__ __align__(16) unsigned char s_x[128 * 64 * 2];  // 16 KiB

    const int bid = blockIdx.x;
    // level 0: 16 b * 50 tiles = 800 ; level 1: 16*13 = 208 ; level 2: 16*4 = 64
    if (bid < 800) {
        run_level<0>(bid, x0, wb0, bb0, wc0, bc0, out, s_w, s_x);
    } else if (bid < 1008) {
        run_level<1>(bid - 800, x1, wb1, bb1, wc1, bc1, out, s_w, s_x);
    } else {
        run_level<2>(bid - 1008, x2, wb2, bb2, wc2, bc2, out, s_w, s_x);
    }
}

extern "C" void kernel_launch(void* const* d_in, const int* in_sizes, int n_in,
                              void* d_out, int out_size, void* d_ws, size_t ws_size,
                              hipStream_t stream) {
    const float* x0  = (const float*)d_in[0];
    const float* x1  = (const float*)d_in[1];
    const float* x2  = (const float*)d_in[2];
    const float* wb0 = (const float*)d_in[3];
    const float* bb0 = (const float*)d_in[4];
    const float* wc0 = (const float*)d_in[5];
    const float* bc0 = (const float*)d_in[6];
    const float* wb1 = (const float*)d_in[7];
    const float* bb1 = (const float*)d_in[8];
    const float* wc1 = (const float*)d_in[9];
    const float* bc1 = (const float*)d_in[10];
    const float* wb2 = (const float*)d_in[11];
    const float* bb2 = (const float*)d_in[12];
    const float* wc2 = (const float*)d_in[13];
    const float* bc2 = (const float*)d_in[14];

    UltralyticsDetect_kernel<<<1072, NTHREADS, 0, stream>>>(
        x0, x1, x2,
        wb0, bb0, wc0, bc0,
        wb1, bb1, wc1, bc1,
        wb2, bb2, wc2, bc2,
        (float*)d_out);
}

// Round 3
// 63.273 us; speedup vs baseline: 1.1785x; 1.1785x over previous
//
#include <hip/hip_runtime.h>

// UltralyticsDetect head, fused: per-level 1x1-conv GEMM (M=144, K=C, N=B*HW)
// in bf16 MFMA + in-register DFL softmax decode + output assembly.
// Output: (16, 8400, 84) f32.
//
// R3: uniform 64-anchor tiles (balanced blocks), long levels dispatched first,
// register prefetch of next X chunk (T14 async-stage split), nontemporal
// output stores (via ext_vector f32x4 — clang rejects HIP_vector_type).

typedef __bf16 bf16x8 __attribute__((ext_vector_type(8)));
typedef float  f32x4  __attribute__((ext_vector_type(4)));

#define NTHREADS 256

// round-half-up f32 -> bf16, pack two into one u32 (a -> low16, b -> high16)
__device__ __forceinline__ unsigned int pack_bf16(float a, float b) {
    unsigned int ua = __builtin_bit_cast(unsigned int, a);
    unsigned int ub = __builtin_bit_cast(unsigned int, b);
    return ((ua + 0x8000u) >> 16) | ((ub + 0x8000u) & 0xffff0000u);
}

// LDS tile: row-major [row][64 bf16] = 128B rows, XOR-swizzled to kill the
// 32-way ds_read_b128 bank conflict (G4: byte ^= (row&7)<<4).
__device__ __forceinline__ int swz(int row, int kbyte) {
    return row * 128 + (kbyte ^ ((row & 7) << 4));
}

template <int LVL>
__device__ __forceinline__ void run_level(
        int rb,
        const float* __restrict__ x,
        const float* __restrict__ wbox, const float* __restrict__ bbox,
        const float* __restrict__ wcls, const float* __restrict__ bcls,
        float* __restrict__ out,
        unsigned char* s_w, unsigned char* s_x) {

    constexpr int   C      = (LVL == 0) ? 256 : 512;
    constexpr int   GW     = (LVL == 0) ? 80 : (LVL == 1 ? 40 : 20);
    constexpr int   HW     = GW * GW;
    constexpr int   AOFF   = (LVL == 0) ? 0 : (LVL == 1 ? 6400 : 8000);
    constexpr float STRIDE = (LVL == 0) ? 8.0f : (LVL == 1 ? 16.0f : 32.0f);
    constexpr int   TPB    = (HW + 63) / 64;   // 64-anchor tiles per image

    const int b    = rb / TPB;
    const int tile = rb % TPB;
    const int hw0  = tile * 64;
    const int nv   = (HW - hw0 < 64) ? (HW - hw0) : 64;  // valid anchors

    const int tid  = threadIdx.x;
    const int wv   = tid >> 6;        // wave 0..3
    const int lane = tid & 63;
    const int col  = lane & 15;       // MFMA n/col lane
    const int q4   = lane >> 4;       // MFMA row-quarter

    const float* xb = x + (size_t)b * C * HW;

    // X staging: thread -> (anchor = lane, k-group base = wave)
    const int anc  = lane;
    const int kgb  = wv;                              // 0..3
    const int ancc = (anc < nv) ? anc : (nv - 1);     // clamp OOB anchors
    const float* xcol = xb + hw0 + ancc;

    f32x4 acc[9];
#pragma unroll
    for (int m = 0; m < 9; ++m) acc[m] = (f32x4){0.f, 0.f, 0.f, 0.f};

    // ---- prologue: prefetch X chunk 0 into registers ----
    float xv[2][8];
#pragma unroll
    for (int i = 0; i < 2; ++i) {
        const float* p = xcol + (size_t)((kgb + 4 * i) * 8) * HW;
#pragma unroll
        for (int j = 0; j < 8; ++j) xv[i][j] = p[(size_t)j * HW];
    }

    const int nkc = C / 64;
    for (int kc = 0; kc < nkc; ++kc) {
        const int k0 = kc * 64;
        __syncthreads();   // previous iteration's LDS reads complete

        // ---- X: pack prefetched regs -> LDS (transposed [anchor][k]) ----
#pragma unroll
        for (int i = 0; i < 2; ++i) {
            const int kg = kgb + 4 * i;
            uint4 q;
            q.x = pack_bf16(xv[i][0], xv[i][1]);
            q.y = pack_bf16(xv[i][2], xv[i][3]);
            q.z = pack_bf16(xv[i][4], xv[i][5]);
            q.w = pack_bf16(xv[i][6], xv[i][7]);
            *(uint4*)(s_x + swz(anc, kg * 16)) = q;
        }

        // ---- issue next X chunk's loads now (hidden under W-stage+MFMA) ----
        if (kc + 1 < nkc) {
            const int k0n = k0 + 64;
#pragma unroll
            for (int i = 0; i < 2; ++i) {
                const float* p = xcol + (size_t)(k0n + (kgb + 4 * i) * 8) * HW;
#pragma unroll
                for (int j = 0; j < 8; ++j) xv[i][j] = p[(size_t)j * HW];
            }
        }

        // ---- stage W chunk: 144 rows x 64 k, f32 -> bf16, swizzled ----
#pragma unroll
        for (int i = 0; i < 5; ++i) {
            int u = tid + i * 256;
            if (u < 1152) {
                int row = u >> 3, kg = u & 7;
                const float* src = (row < 64) ? (wbox + row * C)
                                              : (wcls + (row - 64) * C);
                src += k0 + kg * 8;
                const float4 f0 = *(const float4*)(src);
                const float4 f1 = *(const float4*)(src + 4);
                uint4 p;
                p.x = pack_bf16(f0.x, f0.y);
                p.y = pack_bf16(f0.z, f0.w);
                p.z = pack_bf16(f1.x, f1.y);
                p.w = pack_bf16(f1.z, f1.w);
                *(uint4*)(s_w + swz(row, kg * 16)) = p;
            }
        }

        __syncthreads();

        // ---- MFMA: 2 k-steps of 32, 9 M-tiles x 1 N-tile per wave ----
#pragma unroll
        for (int ks = 0; ks < 2; ++ks) {
            const int kbyte = ks * 64 + q4 * 16;
            const bf16x8 bf = *(const bf16x8*)(s_x + swz(wv * 16 + col, kbyte));
#pragma unroll
            for (int m = 0; m < 9; ++m) {
                const bf16x8 af = *(const bf16x8*)(s_w + swz(m * 16 + col, kbyte));
                acc[m] = __builtin_amdgcn_mfma_f32_16x16x32_bf16(af, bf, acc[m], 0, 0, 0);
            }
        }
    }

    // ---- epilogue: in-register DFL decode + store ----
    // D layout (m89): value[r] = D[mtile*16 + q4*4 + r][col]
    float4 bcv[5];
#pragma unroll
    for (int m = 0; m < 5; ++m)
        bcv[m] = *(const float4*)(bcls + m * 16 + q4 * 4);

    const float LOG2E = 1.44269504088896f;

    const int alocal = wv * 16 + col;
    const bool valid = alocal < nv;
    const int hw = hw0 + alocal;

    float dist[4];
#pragma unroll
    for (int g = 0; g < 4; ++g) {
        const float4 bbv = *(const float4*)(bbox + g * 16 + q4 * 4);
        const float v0 = acc[g][0] + bbv.x;
        const float v1 = acc[g][1] + bbv.y;
        const float v2 = acc[g][2] + bbv.z;
        const float v3 = acc[g][3] + bbv.w;
        // softmax over 16 bins: 4 regs x 4 lanes (col, col+16, col+32, col+48)
        float mx = fmaxf(fmaxf(v0, v1), fmaxf(v2, v3));
        mx = fmaxf(mx, __shfl_xor(mx, 16));
        mx = fmaxf(mx, __shfl_xor(mx, 32));
        const float e0 = __builtin_amdgcn_exp2f((v0 - mx) * LOG2E);
        const float e1 = __builtin_amdgcn_exp2f((v1 - mx) * LOG2E);
        const float e2 = __builtin_amdgcn_exp2f((v2 - mx) * LOG2E);
        const float e3 = __builtin_amdgcn_exp2f((v3 - mx) * LOG2E);
        float s  = e0 + e1 + e2 + e3;
        float ws = e1 + 2.f * e2 + 3.f * e3 + (float)(q4 * 4) * s;
        s  += __shfl_xor(s, 16);
        s  += __shfl_xor(s, 32);
        ws += __shfl_xor(ws, 16);
        ws += __shfl_xor(ws, 32);
        dist[g] = ws / s;
    }

    if (valid) {
        const size_t obase = ((size_t)b * 8400 + AOFF + hw) * 84;
        if (q4 == 0) {
            const float ax = (float)(hw % GW) + 0.5f;
            const float ay = (float)(hw / GW) + 0.5f;
            f32x4 bx;
            bx[0] = (ax + 0.5f * (dist[2] - dist[0])) * STRIDE;
            bx[1] = (ay + 0.5f * (dist[3] - dist[1])) * STRIDE;
            bx[2] = (dist[0] + dist[2]) * STRIDE;
            bx[3] = (dist[1] + dist[3]) * STRIDE;
            __builtin_nontemporal_store(bx, (f32x4*)(out + obase));
        }
#pragma unroll
        for (int m = 0; m < 5; ++m) {
            f32x4 v;
            v[0] = acc[m + 4][0] + bcv[m].x;
            v[1] = acc[m + 4][1] + bcv[m].y;
            v[2] = acc[m + 4][2] + bcv[m].z;
            v[3] = acc[m + 4][3] + bcv[m].w;
            __builtin_nontemporal_store(v, (f32x4*)(out + obase + 4 + m * 16 + q4 * 4));
        }
    }
}

__global__ __launch_bounds__(NTHREADS, 4)
void UltralyticsDetect_kernel(
        const float* __restrict__ x0, const float* __restrict__ x1, const float* __restrict__ x2,
        const float* __restrict__ wb0, const float* __restrict__ bb0,
        const float* __restrict__ wc0, const float* __restrict__ bc0,
        const float* __restrict__ wb1, const float* __restrict__ bb1,
        const float* __restrict__ wc1, const float* __restrict__ bc1,
        const float* __restrict__ wb2, const float* __restrict__ bb2,
        const float* __restrict__ wc2, const float* __restrict__ bc2,
        float* __restrict__ out) {

    __shared__ __align__(16) unsigned char s_w[144 * 64 * 2];  // 18 KiB
    __shared__ __align__(16) unsigned char s_x[64 * 64 * 2];   //  8 KiB

    const int bid = blockIdx.x;
    // Long (K=512) levels first so the tail is filled by short level-0 blocks:
    // level 1: 16 b * 25 tiles = 400 ; level 2: 16*7 = 112 ; level 0: 16*100 = 1600
    if (bid < 400) {
        run_level<1>(bid, x1, wb1, bb1, wc1, bc1, out, s_w, s_x);
    } else if (bid < 512) {
        run_level<2>(bid - 400, x2, wb2, bb2, wc2, bc2, out, s_w, s_x);
    } else {
        run_level<0>(bid - 512, x0, wb0, bb0, wc0, bc0, out, s_w, s_x);
    }
}

extern "C" void kernel_launch(void* const* d_in, const int* in_sizes, int n_in,
                              void* d_out, int out_size, void* d_ws, size_t ws_size,
                              hipStream_t stream) {
    const float* x0  = (const float*)d_in[0];
    const float* x1  = (const float*)d_in[1];
    const float* x2  = (const float*)d_in[2];
    const float* wb0 = (const float*)d_in[3];
    const float* bb0 = (const float*)d_in[4];
    const float* wc0 = (const float*)d_in[5];
    const float* bc0 = (const float*)d_in[6];
    const float* wb1 = (const float*)d_in[7];
    const float* bb1 = (const float*)d_in[8];
    const float* wc1 = (const float*)d_in[9];
    const float* bc1 = (const float*)d_in[10];
    const float* wb2 = (const float*)d_in[11];
    const float* bb2 = (const float*)d_in[12];
    const float* wc2 = (const float*)d_in[13];
    const float* bc2 = (const float*)d_in[14];

    UltralyticsDetect_kernel<<<2112, NTHREADS, 0, stream>>>(
        x0, x1, x2,
        wb0, bb0, wc0, bc0,
        wb1, bb1, wc1, bc1,
        wb2, bb2, wc2, bc2,
        (float*)d_out);
}